// Round 1
// 185.652 us; speedup vs baseline: 1.0453x; 1.0453x over previous
//
#include <hip/hip_runtime.h>
#include <math.h>

#define B_ 64
#define F_ 32
#define S_ 512
#define P_ 96
#define E_ 8
#define H_ 2048
#define M_ 2048   // B_*F_ rows, m = b*F_ + f

// ---- k_experts: 512 threads (8 waves), 1 block/CU, 2-phase pipelined staging ----
// Old structure: stage -> drain -> MFMA -> barrier (0-phase, full latency exposed
// every K-step; MfmaUtil 17%). New: double-buffered W1/X tiles, STAGE(t+1) issued
// before compute(t), one barrier per step; GEMM2 for chunk ht runs inside the
// first K-step of chunk ht+1 (hides cross-chunk staging); W2 panel staged to LDS
// once per chunk (was read 8x redundantly from L2 by every wave).
#define BM 128            // m rows per block
#define BH 128            // h per chunk
#define BK 64             // k per staged tile
#define ZSPLIT 2
#define HPZ (H_ / ZSPLIT) // 1024 h per z-block
#define NHT (HPZ / BH)    // 8 h-chunks per block
#define NKC (S_ / BK)     // 8 k-steps per chunk
#define HPITCH 136        // Hs pitch: 128 + 8 skew

typedef __bf16 bf16x8 __attribute__((ext_vector_type(8)));
typedef __bf16 bf16x4 __attribute__((ext_vector_type(4)));
typedef float f32x4 __attribute__((ext_vector_type(4)));

#define MFMA16(a, b, c) __builtin_amdgcn_mfma_f32_16x16x32_bf16((a), (b), (c), 0, 0, 0)

// async global->LDS, 16B per lane; LDS dest is wave-uniform base + lane*16
#define GLL16(gp, lp) __builtin_amdgcn_global_load_lds(                     \
    (const __attribute__((address_space(1))) void*)(gp),                    \
    (__attribute__((address_space(3))) void*)(lp), 16, 0, 0)

// sigmoid-approx gelu: x * sigmoid(1.702 x)  (absmax 0.0098 measured — 17x margin)
__device__ __forceinline__ float fast_gelu(float x) {
  float e = __builtin_amdgcn_exp2f(-2.45546696f * x);
  return x * __builtin_amdgcn_rcpf(1.0f + e);
}

// =================== k_prep (256 threads): transposes + convert + gates + out-zero ===================
// blocks [0,2048):     W1 [E][S][H] f32 -> w1t [E][H][S] bf16   (64x64 tiles)
// blocks [2048,2560):  W2 [E][H][P] f32 -> w2t [E][P][H] bf16   (64h x 48p tiles)
// blocks [2560,3072):  x convert (8 elems/thread)
// blocks [3072,3584):  gates (4 rows per block)
// blocks [3584,3776):  zero out[M*P]  (replaces hipMemsetAsync -> one fewer dispatch)
#define PREP_GRID 3776

__global__ __launch_bounds__(256) void k_prep(const float* __restrict__ x,
                                              const float* __restrict__ te,
                                              const float* __restrict__ Wg,
                                              const float* __restrict__ bg,
                                              const float* __restrict__ W1,
                                              const float* __restrict__ W2,
                                              __bf16* __restrict__ xbf,
                                              __bf16* __restrict__ w1t,
                                              __bf16* __restrict__ w2t,
                                              float* __restrict__ gates,
                                              float* __restrict__ out) {
  __shared__ float tile[64 * 65];
  const int blk = blockIdx.x;
  const int tid = threadIdx.x;

  if (blk < 2048) {                       // ---- W1 transpose: tile 64s x 64h
    int e = blk >> 8, tt = blk & 255;
    int si = tt >> 5, hi = tt & 31;
    const float* src = W1 + (size_t)e * S_ * H_ + (size_t)(si * 64) * H_ + hi * 64;
    {
      int row = tid >> 2;
      int cb = (tid & 3) * 16;
#pragma unroll
      for (int k = 0; k < 4; ++k) {
        f32x4 v = *(const f32x4*)(src + (size_t)row * H_ + cb + k * 4);
#pragma unroll
        for (int u = 0; u < 4; ++u) tile[row * 65 + cb + k * 4 + u] = v[u];
      }
    }
    __syncthreads();
    {
      int h = tid >> 2;
      int sb = (tid & 3) * 16;
      __bf16* dst = w1t + (size_t)e * H_ * S_ + (size_t)(hi * 64 + h) * S_ + si * 64 + sb;
      bf16x8 o0, o1;
#pragma unroll
      for (int k = 0; k < 8; ++k) o0[k] = (__bf16)tile[(sb + k) * 65 + h];
#pragma unroll
      for (int k = 0; k < 8; ++k) o1[k] = (__bf16)tile[(sb + 8 + k) * 65 + h];
      *(bf16x8*)dst = o0;
      *(bf16x8*)(dst + 8) = o1;
    }
    return;
  }
  if (blk < 2560) {                       // ---- W2 transpose: tile 64h x 48p
    int t = blk - 2048;
    int e = t >> 6, hi = (t >> 1) & 31, ph = t & 1;
    const float* src = W2 + (size_t)e * H_ * P_ + (size_t)(hi * 64) * P_ + ph * 48;
    {
      int h = tid & 63;
      int seg = tid >> 6;
#pragma unroll
      for (int k = 0; k < 3; ++k) {
        f32x4 v = *(const f32x4*)(src + (size_t)h * P_ + seg * 12 + k * 4);
#pragma unroll
        for (int u = 0; u < 4; ++u) tile[h * 49 + seg * 12 + k * 4 + u] = v[u];
      }
    }
    __syncthreads();
    if (tid < 192) {
      int p = tid >> 2;
      int hb = (tid & 3) * 16;
      __bf16* dst = w2t + (size_t)e * P_ * H_ + (size_t)(ph * 48 + p) * H_ + hi * 64 + hb;
      bf16x8 o0, o1;
#pragma unroll
      for (int k = 0; k < 8; ++k) o0[k] = (__bf16)tile[(hb + k) * 49 + p];
#pragma unroll
      for (int k = 0; k < 8; ++k) o1[k] = (__bf16)tile[(hb + 8 + k) * 49 + p];
      *(bf16x8*)dst = o0;
      *(bf16x8*)(dst + 8) = o1;
    }
    return;
  }
  if (blk < 3072) {                       // ---- x convert
    size_t i = (size_t)(blk - 2560) * 2048 + (size_t)tid * 8;
#pragma unroll
    for (int k = 0; k < 2; ++k) {
      f32x4 v = *(const f32x4*)(x + i + k * 4);
      bf16x4 o = {(__bf16)v[0], (__bf16)v[1], (__bf16)v[2], (__bf16)v[3]};
      *(bf16x4*)(xbf + i + k * 4) = o;
    }
    return;
  }
  if (blk < 3584) {                       // ---- gates: one wave per row m
    int wave = tid >> 6, lane = tid & 63;
    int m = (blk - 3072) * 4 + wave;
    const float* trow = te + (size_t)m * S_;
    float acc[E_];
#pragma unroll
    for (int e = 0; e < E_; ++e) acc[e] = 0.f;
    for (int s = lane; s < S_; s += 64) {
      float t = trow[s];
      const f32x4* wgr = (const f32x4*)(Wg + s * E_);
      f32x4 a = wgr[0], b = wgr[1];
      acc[0] += t * a[0]; acc[1] += t * a[1]; acc[2] += t * a[2]; acc[3] += t * a[3];
      acc[4] += t * b[0]; acc[5] += t * b[1]; acc[6] += t * b[2]; acc[7] += t * b[3];
    }
#pragma unroll
    for (int e = 0; e < E_; ++e) {
#pragma unroll
      for (int off = 32; off > 0; off >>= 1) acc[e] += __shfl_xor(acc[e], off, 64);
    }
    if (lane == 0) {
      float lg[E_];
      float m1 = -3.4e38f, m2 = -3.4e38f;
#pragma unroll
      for (int e = 0; e < E_; ++e) {
        float v = acc[e] + bg[e];
        lg[e] = v;
        if (v > m1) { m2 = m1; m1 = v; }
        else if (v > m2) { m2 = v; }
      }
      float den = 0.f, sm[E_];
#pragma unroll
      for (int e = 0; e < E_; ++e) { sm[e] = expf(lg[e] - m1); den += sm[e]; }
      float inv = 1.f / den;
      float dmax = -3.4e38f, dec[E_];
#pragma unroll
      for (int e = 0; e < E_; ++e) {
        float p = sm[e] * inv;
        float d = (lg[e] < m2) ? (10.f * logf(p + 1.f)) : (10.f * (expf(p) - 1.f));
        dec[e] = d;
        dmax = fmaxf(dmax, d);
      }
      float dden = 0.f;
#pragma unroll
      for (int e = 0; e < E_; ++e) { dec[e] = expf(dec[e] - dmax); dden += dec[e]; }
      float dinv = 1.f / dden;
#pragma unroll
      for (int e = 0; e < E_; ++e) gates[m * E_ + e] = dec[e] * dinv;
    }
    return;
  }
  // ---- zero the accumulated output region [0, M*P) ; loss slots are stored, not accumulated
  {
    size_t i = (size_t)(blk - 3584) * 1024 + (size_t)tid * 4;
    f32x4 z4 = {0.f, 0.f, 0.f, 0.f};
    *(f32x4*)(out + i) = z4;
  }
}

// =================== k_experts: grid (E_, 16, ZSPLIT+1), 512 threads ===================
// Per block: 128m rows x 1024h slice (8 chunks of 128h). Per chunk:
//   2-phase pipelined GEMM1: STAGE(t+1) into the alternate LDS buffer, then
//   ds_read+MFMA tile t, one __syncthreads per step (vmcnt+lgkm drain + barrier).
//   gelu -> Hs[m][h]; GEMM2(chunk ht) is executed inside the FIRST K-step of
//   chunk ht+1 so the staging latency of the next tile hides under its MFMAs.
//   W2 panel [96p][128h] for chunk ht is staged to LDS (XOR-swizzled) during the
//   LAST K-step of chunk ht, consumed by GEMM2 one step later.
// Single gated atomic epilogue per block (16 adds/output elem, was 32).
__global__ __launch_bounds__(512, 2) void k_experts(
    const __bf16* __restrict__ xbf,   // [M][S]
    const __bf16* __restrict__ w1t,   // [E][H][S]
    const __bf16* __restrict__ w2t,   // [E][P][H]
    const float* __restrict__ b1,     // [E][H]
    const float* __restrict__ b2,     // [E][P]
    const float* __restrict__ gates,  // [M][E]
    float* __restrict__ out)          // [M][P] (+2 loss slots)
{
  __shared__ __align__(16) __bf16 W1s[2][BH * BK];   // 2 x 16 KB, [h][k], XOR granule swizzle
  __shared__ __align__(16) __bf16 Xs[2][BM * BK];    // 2 x 16 KB, [m][k], XOR granule swizzle
  __shared__ __align__(16) __bf16 W2s[P_ * BH];      // 24 KB, [p][h], XOR granule swizzle
  __shared__ __align__(16) __bf16 Hs[BM * HPITCH];   // 34.8 KB [m][h]   -> 124.9 KB total, 1 blk/CU

  const int tid = threadIdx.x;

  if (blockIdx.z == ZSPLIT) {      // ---- loss block (others exit)
    if (blockIdx.x != 0 || blockIdx.y != 0) return;
    float* gsum = (float*)&Hs[0];
    float* cvs  = gsum + F_ * E_;
    float* ents = cvs + F_;
    if (tid < 256) {
      int f = tid >> 3, ee = tid & 7;
      float s = 0.f;
      for (int b = 0; b < B_; ++b) s += gates[(size_t)(b * F_ + f) * E_ + ee];
      gsum[f * E_ + ee] = s;
    }
    __syncthreads();
    if (tid < F_) {
      float mean = 0.f;
#pragma unroll
      for (int k = 0; k < E_; ++k) mean += gsum[tid * E_ + k];
      mean *= (1.f / E_);
      float ss = 0.f;
#pragma unroll
      for (int k = 0; k < E_; ++k) { float d = gsum[tid * E_ + k] - mean; ss += d * d; }
      float var = (float)P_ * ss / (float)(E_ * P_ - 1);
      cvs[tid] = var / (mean * mean + 1e-10f);
      float ent = 0.f;
#pragma unroll
      for (int k = 0; k < E_; ++k) { float g = gsum[tid * E_ + k] * (1.f / B_); ent += -g * logf(g + 1e-8f); }
      ents[tid] = ent * (1.f / E_);
    }
    __syncthreads();
    if (tid == 0) {
      float a = 0.f, b = 0.f;
      for (int k = 0; k < F_; ++k) { a += cvs[k]; b += ents[k]; }
      out[(size_t)M_ * P_ + 0] = a;
      out[(size_t)M_ * P_ + 1] = b;
    }
    return;
  }

  const int wave = tid >> 6, lane = tid & 63;
  const int l15 = lane & 15, quad = lane >> 4;
  const int e = blockIdx.x;
  const int m0 = blockIdx.y * BM;
  const int hz = blockIdx.z * HPZ;

  // staging decomposition: lane -> (row-in-8-group srl, granule sg); swizzle sg^srl
  const int sg = lane & 7;
  const int srl = lane >> 3;            // 0..7
  const int gcol = ((sg ^ srl) * 8);    // swizzled source column (elements)

  const __bf16* w1base = w1t + ((size_t)e * H_ + hz + wave * 16 + srl) * S_ + gcol;
  const __bf16* xg = xbf + (size_t)(m0 + wave * 16 + srl) * S_ + gcol;
  const __bf16* w2z = w2t + (size_t)e * P_ * H_ + hz;

  // GEMM1 wave quadrant: 64h x 32m per wave (2x4 wave grid over 128x128)
  const int hq = (wave & 1) * 64;
  const int mq = (wave >> 1) * 32;
  // GEMM2: 16 m-rows per wave
  const int w16 = wave * 16;

  const f32x4 fz = {0.f, 0.f, 0.f, 0.f};
  f32x4 acc1[4][2];
  f32x4 acc2[6];
#pragma unroll
  for (int j = 0; j < 6; ++j) acc2[j] = fz;

  // ---- stage one 128x64 W1 tile + 128x64 X tile into buffer b (4 GLL16/wave) ----
  auto STAGE = [&](int ht_, int kc_, int b) {
    const __bf16* w1p = w1base + (size_t)(ht_ * BH) * S_ + kc_ * BK;
    const __bf16* xp  = xg + kc_ * BK;
#pragma unroll
    for (int p = 0; p < 2; ++p) {
      GLL16(w1p + (size_t)(p * 8) * S_, &W1s[b][(wave * 16 + p * 8) * BK]);
      GLL16(xp  + (size_t)(p * 8) * S_, &Xs[b][(wave * 16 + p * 8) * BK]);
    }
  };

  // ---- stage W2 panel [96p][128h] for chunk ht_ (3 GLL16/wave), swizzled source ----
  auto STAGEW2 = [&](int ht_) {
#pragma unroll
    for (int p = 0; p < 3; ++p) {
      int r2 = wave * 12 + p * 4 + quad;        // p-row 0..95
      GLL16(w2z + (size_t)r2 * H_ + ht_ * BH + ((l15 ^ (r2 & 7)) * 8),
            &W2s[(wave * 12 + p * 4) * BH]);
    }
  };

  // ---- GEMM1 compute of the tile in buffer b: 16 MFMA/wave ----
  auto COMPUTE = [&](int b) {
#pragma unroll
    for (int kk = 0; kk < 2; ++kk) {
      bf16x8 af[4], bx[2];
#pragma unroll
      for (int i = 0; i < 4; ++i) {
        int r = hq + i * 16 + l15;
        af[i] = *(const bf16x8*)&W1s[b][r * BK + (((kk * 4 + quad) ^ (r & 7)) * 8)];
      }
#pragma unroll
      for (int j = 0; j < 2; ++j) {
        int r = mq + j * 16 + l15;
        bx[j] = *(const bf16x8*)&Xs[b][r * BK + (((kk * 4 + quad) ^ (r & 7)) * 8)];
      }
#pragma unroll
      for (int i = 0; i < 4; ++i)
#pragma unroll
        for (int j = 0; j < 2; ++j)
          acc1[i][j] = MFMA16(af[i], bx[j], acc1[i][j]);
    }
  };

  // ---- GEMM2 over the Hs/W2s chunk currently in LDS: 24 MFMA/wave ----
  auto GEMM2 = [&]() {
#pragma unroll
    for (int kk = 0; kk < 4; ++kk) {
      bf16x8 a = *(const bf16x8*)&Hs[(w16 + l15) * HPITCH + kk * 32 + quad * 8];
#pragma unroll
      for (int j = 0; j < 6; ++j) {
        bf16x8 bb = *(const bf16x8*)&W2s[(j * 16 + l15) * BH + (((kk * 4 + quad) ^ (l15 & 7)) * 8)];
        acc2[j] = MFMA16(a, bb, acc2[j]);
      }
    }
  };

  // ---- bias + gelu -> Hs[m][h] (C-layout: col=l15=m, row=quad*4+r=h-local) ----
  auto GELU = [&](int ht_) {
    const float* b1w = b1 + (size_t)e * H_ + hz + ht_ * BH + hq;
#pragma unroll
    for (int i = 0; i < 4; ++i) {
      f32x4 bv = *(const f32x4*)(b1w + i * 16 + quad * 4);
#pragma unroll
      for (int j = 0; j < 2; ++j) {
        bf16x4 hv;
#pragma unroll
        for (int r = 0; r < 4; ++r)
          hv[r] = (__bf16)fast_gelu(acc1[i][j][r] + bv[r]);
        *(bf16x4*)&Hs[(mq + j * 16 + l15) * HPITCH + hq + i * 16 + quad * 4] = hv;
      }
    }
  };

  // ================== main pipeline ==================
  STAGE(0, 0, 0);
  __syncthreads();

  for (int ht = 0; ht < NHT; ++ht) {
#pragma unroll
    for (int i = 0; i < 4; ++i)
#pragma unroll
      for (int j = 0; j < 2; ++j) acc1[i][j] = fz;

    int bsel = 0;   // constant-folded by the unrolled kc loop (t even at chunk start)
#pragma unroll
    for (int kc = 0; kc < NKC; ++kc) {
      if (kc < NKC - 1) {
        STAGE(ht, kc + 1, bsel ^ 1);
      } else {
        if (ht < NHT - 1) STAGE(ht + 1, 0, bsel ^ 1);
        STAGEW2(ht);                    // W2 panel for this chunk, consumed next step
      }
      if (kc == 0 && ht > 0) GEMM2();   // previous chunk's GEMM2 hides staging latency
      COMPUTE(bsel);
      __syncthreads();                  // vmcnt+lgkm drain + barrier: next tile ready
      bsel ^= 1;
    }
    GELU(ht);
    __syncthreads();                    // Hs visible to all waves
  }
  GEMM2();                              // last chunk

  // ---- epilogue: out[m,p] += gates[m,e] * (acc + b2 (z==0 only)) ----
#pragma unroll
  for (int r = 0; r < 4; ++r) {
    int m = m0 + w16 + quad * 4 + r;
    float g = gates[m * E_ + e];
#pragma unroll
    for (int j = 0; j < 6; ++j) {
      int col = j * 16 + l15;
      float v = acc2[j][r];
      if (blockIdx.z == 0) v += b2[e * P_ + col];
      atomicAdd(&out[(size_t)m * P_ + col], g * v);
    }
  }
}

extern "C" void kernel_launch(void* const* d_in, const int* in_sizes, int n_in,
                              void* d_out, int out_size, void* d_ws, size_t ws_size,
                              hipStream_t stream) {
  const float* x  = (const float*)d_in[0];
  const float* te = (const float*)d_in[1];
  const float* Wg = (const float*)d_in[2];
  const float* bg = (const float*)d_in[3];
  const float* W1 = (const float*)d_in[4];
  const float* b1 = (const float*)d_in[5];
  const float* W2 = (const float*)d_in[6];
  const float* b2 = (const float*)d_in[7];
  float* out = (float*)d_out;

  char* ws = (char*)d_ws;
  float* gates = (float*)ws;                                    // 65,536 B
  __bf16* xbf  = (__bf16*)(ws + 65536);                         // 2 MB
  __bf16* w1t  = (__bf16*)(ws + 65536 + 2097152);               // 16 MB
  __bf16* w2t  = (__bf16*)(ws + 65536 + 2097152 + 16777216);    // 3 MB

  k_prep<<<PREP_GRID, 256, 0, stream>>>(x, te, Wg, bg, W1, W2, xbf, w1t, w2t, gates, out);
  k_experts<<<dim3(E_, M_ / BM, ZSPLIT + 1), 512, 0, stream>>>(xbf, w1t, w2t, b1, b2, gates, out);
}